// Round 6
// baseline (242.761 us; speedup 1.0000x reference)
//
#include <hip/hip_runtime.h>

typedef float  f32x4_t  __attribute__((ext_vector_type(4)));
typedef __bf16 bf16x8_t __attribute__((ext_vector_type(8)));

#define BS   512
#define Mn   64
#define Kn   32
#define Fn   64
#define ROWS 2048   // Mn*Kn

__device__ __forceinline__ void load_tile(const float* __restrict__ z_mk,
                                          size_t rb, int low, int gr, float4* r) {
    const float* zr = z_mk + (rb + low) * 64;
    r[0] = *(const float4*)(zr + 0 * 32 + gr * 8);
    r[1] = *(const float4*)(zr + 0 * 32 + gr * 8 + 4);
    r[2] = *(const float4*)(zr + 1 * 32 + gr * 8);
    r[3] = *(const float4*)(zr + 1 * 32 + gr * 8 + 4);
}

// ---------------- Kernel A: edges + messages -----------------
// grid 2048 = 512 batches x 4 m-quarters; 256 threads (4 waves).
// Cross-iteration software pipeline: next tile-pair's 8 global loads are
// issued BEFORE the current pair's MFMA+epilogue, so ~8KB/wave stays in
// flight through the epilogue instead of only during the explicit wait.
__global__ __launch_bounds__(256, 4) void gnn_edges(
    const float* __restrict__ z_mk, const float* __restrict__ z_m,
    const float* __restrict__ z_k,  const float* __restrict__ Wedge,
    const float* __restrict__ Wm,   const float* __restrict__ Wk,
    float* __restrict__ out0, float* __restrict__ ws)
{
    __shared__ __align__(16) float s_all[8480];
    float* s_wzm = s_all;          // 1024 (16 x 64)
    float* s_wzk = s_all + 1024;   // 2080 (32 x 65)
    float* U     = s_all + 3104;   // 5376 phase-unioned

    const int tid  = threadIdx.x;
    const int bid  = blockIdx.x;
    const int b    = bid >> 2;
    const int mq   = bid & 3;      // m-quarter
    const int lane = tid & 63;
    const int wave = tid >> 6;     // 0..3
    const int low  = lane & 15;
    const int gr   = lane >> 4;
    const int f    = lane;

    // ---- P0: stage z_m quarter (16 rows) + z_k (32 rows) ----
    {
        const float4* src = (const float4*)(z_m + ((size_t)b * Mn + mq * 16) * Fn);
        float4* dst = (float4*)U;
        for (int i = tid; i < 16 * Fn / 4; i += 256) dst[i] = src[i];
        const float4* src2 = (const float4*)(z_k + (size_t)b * Kn * Fn);
        float4* dst2 = (float4*)(U + 1024);
        for (int i = tid; i < Kn * Fn / 4; i += 256) dst2[i] = src2[i];
    }
    __syncthreads();

    // ---- P1: Wz_m (16 rows), Wz_k (32 rows), fp32 ----
    {
        float acc[4] = {0.f, 0.f, 0.f, 0.f};
        for (int c0 = 0; c0 < Fn; c0 += 16) {
            float w[16];
            #pragma unroll
            for (int cc = 0; cc < 16; ++cc) w[cc] = Wm[(c0 + cc) * Fn + f];
            #pragma unroll
            for (int t = 0; t < 4; ++t) {
                const float* zp = U + (wave + 4 * t) * Fn + c0;
                #pragma unroll
                for (int q = 0; q < 4; ++q) {
                    float4 z = *(const float4*)(zp + q * 4);
                    acc[t] += z.x * w[4*q] + z.y * w[4*q+1] + z.z * w[4*q+2] + z.w * w[4*q+3];
                }
            }
        }
        #pragma unroll
        for (int t = 0; t < 4; ++t) s_wzm[(wave + 4 * t) * Fn + f] = acc[t];
    }
    {
        float acc[8] = {0.f};
        for (int c0 = 0; c0 < Fn; c0 += 16) {
            float w[16];
            #pragma unroll
            for (int cc = 0; cc < 16; ++cc) w[cc] = Wk[(c0 + cc) * Fn + f];
            #pragma unroll
            for (int t = 0; t < 8; ++t) {
                const float* zp = U + 1024 + (wave + 4 * t) * Fn + c0;
                #pragma unroll
                for (int q = 0; q < 4; ++q) {
                    float4 z = *(const float4*)(zp + q * 4);
                    acc[t] += z.x * w[4*q] + z.y * w[4*q+1] + z.z * w[4*q+2] + z.w * w[4*q+3];
                }
            }
        }
        #pragma unroll
        for (int t = 0; t < 8; ++t) s_wzk[(wave + 4 * t) * 65 + f] = acc[t];
    }
    __syncthreads();   // z staging dead

    // ---- P2: stage Wedge (padded 65) ----
    for (int i = tid; i < Fn * Fn; i += 256)
        U[(i >> 6) * 65 + (i & 63)] = Wedge[i];
    __syncthreads();

    // ---- P3: B fragments ----
    bf16x8_t Bf[2][4];
    #pragma unroll
    for (int ks = 0; ks < 2; ++ks)
        #pragma unroll
        for (int n = 0; n < 4; ++n)
            #pragma unroll
            for (int i = 0; i < 8; ++i)
                Bf[ks][n][i] = (__bf16)U[(ks * 32 + gr * 8 + i) * 65 + n * 16 + low];
    __syncthreads();   // Wedge dead

    // ---- P4: zero message accumulators ----
    for (int i = tid; i < 3072; i += 256) U[i] = 0.f;

    // hoist loop-invariant Wz_k values: kk = p*16 + gr*4 + j, fc = n*16 + low
    const int p = wave & 1;
    float wzk_r[4][4];
    #pragma unroll
    for (int j = 0; j < 4; ++j)
        #pragma unroll
        for (int n = 0; n < 4; ++n)
            wzk_r[j][n] = s_wzk[(p * 16 + gr * 4 + j) * 65 + n * 16 + low];
    __syncthreads();

    float* s_mnm = U;                      // 16 x 64
    float* s_mnk = U + 1024;               // 32 x 64
    float* scr   = U + 3072 + wave * 576;  // 16 rows x 36 stride

    // ---- P5: main edge loop, tile pairs, 1-pair-deep pipeline ----
    float nk[4][4];
    #pragma unroll
    for (int j = 0; j < 4; ++j)
        #pragma unroll
        for (int n = 0; n < 4; ++n) nk[j][n] = 0.f;

    const size_t browbase = (size_t)b * ROWS + (size_t)mq * 512;

    auto process = [&](const float4* rr, int ml, size_t rb) {
        bf16x8_t A[2];
        #pragma unroll
        for (int ks = 0; ks < 2; ++ks) {
            float4 qa = rr[2*ks], qb = rr[2*ks+1];
            A[ks][0] = (__bf16)qa.x; A[ks][1] = (__bf16)qa.y;
            A[ks][2] = (__bf16)qa.z; A[ks][3] = (__bf16)qa.w;
            A[ks][4] = (__bf16)qb.x; A[ks][5] = (__bf16)qb.y;
            A[ks][6] = (__bf16)qb.z; A[ks][7] = (__bf16)qb.w;
        }

        f32x4_t acc[4];
        #pragma unroll
        for (int n = 0; n < 4; ++n) acc[n] = (f32x4_t){0.f, 0.f, 0.f, 0.f};
        #pragma unroll
        for (int ks = 0; ks < 2; ++ks)
            #pragma unroll
            for (int n = 0; n < 4; ++n)
                acc[n] = __builtin_amdgcn_mfma_f32_16x16x32_bf16(A[ks], Bf[ks][n], acc[n], 0, 0, 0);

        // epilogue: msgs + LDS transpose -> nontemporal full-line stores
        #pragma unroll
        for (int h = 0; h < 2; ++h) {
            #pragma unroll
            for (int nn = 0; nn < 2; ++nn) {
                const int n  = h * 2 + nn;
                const int fc = n * 16 + low;
                const float wmv = s_wzm[ml * Fn + fc];
                float snm = 0.f;
                #pragma unroll
                for (int j = 0; j < 4; ++j) {
                    float e = acc[n][j] + wmv + wzk_r[j][n];
                    e = e > 0.f ? e : 0.01f * e;
                    scr[(gr * 4 + j) * 36 + nn * 16 + low] = e;
                    nk[j][n] += e;
                    snm += e;
                }
                snm += __shfl_xor(snm, 16);
                snm += __shfl_xor(snm, 32);
                if (gr == 0) atomicAdd(&s_mnm[ml * Fn + fc], snm);
            }
            __builtin_amdgcn_wave_barrier();
            #pragma unroll
            for (int q = 0; q < 2; ++q) {
                f32x4_t v = *(const f32x4_t*)(scr + (q * 8 + (lane >> 3)) * 36 + (lane & 7) * 4);
                __builtin_nontemporal_store(v,
                    (f32x4_t*)(out0 + (rb + q * 8 + (lane >> 3)) * 64 + h * 32 + (lane & 7) * 4));
            }
            __builtin_amdgcn_wave_barrier();
        }
    };

    float4 cur0[4], cur1[4], nxt0[4], nxt1[4];
    load_tile(z_mk, browbase + (size_t)(wave)     * 16, low, gr, cur0);
    load_tile(z_mk, browbase + (size_t)(wave + 4) * 16, low, gr, cur1);

    #pragma unroll 1
    for (int it = 0; it < 4; ++it) {
        const int t0 = wave + 8 * it;
        // issue next pair's 8 loads BEFORE any compute/epilogue of this pair
        if (it + 1 < 4) {
            load_tile(z_mk, browbase + (size_t)(t0 + 8)  * 16, low, gr, nxt0);
            load_tile(z_mk, browbase + (size_t)(t0 + 12) * 16, low, gr, nxt1);
        }

        process(cur0, t0 >> 1,       browbase + (size_t)t0 * 16);
        process(cur1, (t0 + 4) >> 1, browbase + (size_t)(t0 + 4) * 16);

        #pragma unroll
        for (int i = 0; i < 4; ++i) { cur0[i] = nxt0[i]; cur1[i] = nxt1[i]; }
    }

    // flush per-lane msg_nk partials into LDS
    #pragma unroll
    for (int j = 0; j < 4; ++j)
        #pragma unroll
        for (int n = 0; n < 4; ++n)
            atomicAdd(&s_mnk[(p * 16 + gr * 4 + j) * Fn + n * 16 + low], nk[j][n]);
    __syncthreads();

    // ---- P6: messages to workspace ----
    {
        float* dm = ws + (size_t)b * (Mn * Fn) + mq * 16 * Fn;       // complete rows
        for (int i = tid; i < 1024; i += 256) dm[i] = s_mnm[i];
        float* dk = ws + (size_t)BS * Mn * Fn + ((size_t)mq * BS + b) * (Kn * Fn); // partial
        for (int i = tid; i < 2048; i += 256) dk[i] = s_mnk[i];
    }
}

// ---------------- Kernel B: node updates -----------------
__global__ __launch_bounds__(256, 2) void gnn_nodes(
    const float* __restrict__ z_m, const float* __restrict__ z_k,
    const float* __restrict__ Wself_m, const float* __restrict__ Wself_k,
    const float* __restrict__ Wneigh_m, const float* __restrict__ Wneigh_k,
    const float* __restrict__ ws,
    float* __restrict__ out1, float* __restrict__ out2)
{
    __shared__ __align__(16) float s[12288]; // zm 4096 | zk 2048 | mnm 4096 | mnk 2048
    float* s_zm  = s;
    float* s_zk  = s + 4096;
    float* s_mnm = s + 6144;
    float* s_mnk = s + 10240;

    const int tid  = threadIdx.x;
    const int b    = blockIdx.x;
    const int lane = tid & 63;
    const int wave = tid >> 6;
    const int f    = lane;
    const int rg   = wave;

    {
        const float4* src = (const float4*)(z_m + (size_t)b * Mn * Fn);
        for (int i = tid; i < Mn * Fn / 4; i += 256) ((float4*)s_zm)[i] = src[i];
        const float4* src2 = (const float4*)(z_k + (size_t)b * Kn * Fn);
        for (int i = tid; i < Kn * Fn / 4; i += 256) ((float4*)s_zk)[i] = src2[i];
        const float4* srcm = (const float4*)(ws + (size_t)b * Mn * Fn);
        for (int i = tid; i < Mn * Fn / 4; i += 256) ((float4*)s_mnm)[i] = srcm[i];
        const float* base = ws + (size_t)BS * Mn * Fn;
        const float* p0 = base + ((size_t)0 * BS + b) * (Kn * Fn);
        const float* p1 = base + ((size_t)1 * BS + b) * (Kn * Fn);
        const float* p2 = base + ((size_t)2 * BS + b) * (Kn * Fn);
        const float* p3 = base + ((size_t)3 * BS + b) * (Kn * Fn);
        for (int i = tid; i < Kn * Fn; i += 256) s_mnk[i] = p0[i] + p1[i] + p2[i] + p3[i];
    }
    __syncthreads();

    // out1: rows rg + 4t, t=0..15
    {
        float d[16], e[16];
        #pragma unroll
        for (int t = 0; t < 16; ++t) { d[t] = 0.f; e[t] = 0.f; }
        for (int c0 = 0; c0 < Fn; c0 += 16) {
            float wA[16], wB[16];
            #pragma unroll
            for (int cc = 0; cc < 16; ++cc) {
                wA[cc] = Wself_m[(c0 + cc) * Fn + f];
                wB[cc] = Wneigh_m[(c0 + cc) * Fn + f];
            }
            #pragma unroll
            for (int t = 0; t < 16; ++t) {
                const float* zp = s_zm + (rg + 4 * t) * Fn + c0;
                const float* mp = s_mnm + (rg + 4 * t) * Fn + c0;
                #pragma unroll
                for (int q = 0; q < 4; ++q) {
                    float4 z = *(const float4*)(zp + q * 4);
                    float4 m = *(const float4*)(mp + q * 4);
                    d[t] += z.x * wA[4*q] + z.y * wA[4*q+1] + z.z * wA[4*q+2] + z.w * wA[4*q+3];
                    e[t] += m.x * wB[4*q] + m.y * wB[4*q+1] + m.z * wB[4*q+2] + m.w * wB[4*q+3];
                }
            }
        }
        #pragma unroll
        for (int t = 0; t < 16; ++t) {
            float v = d[t] + e[t] * (1.f / 32.f);
            v = v > 0.f ? v : 0.01f * v;
            out1[(size_t)b * Mn * Fn + (rg + 4 * t) * Fn + f] = v;
        }
    }
    // out2: rows rg + 4t, t=0..7
    {
        float d[8], e[8];
        #pragma unroll
        for (int t = 0; t < 8; ++t) { d[t] = 0.f; e[t] = 0.f; }
        for (int c0 = 0; c0 < Fn; c0 += 16) {
            float wA[16], wB[16];
            #pragma unroll
            for (int cc = 0; cc < 16; ++cc) {
                wA[cc] = Wself_k[(c0 + cc) * Fn + f];
                wB[cc] = Wneigh_k[(c0 + cc) * Fn + f];
            }
            #pragma unroll
            for (int t = 0; t < 8; ++t) {
                const float* zp = s_zk + (rg + 4 * t) * Fn + c0;
                const float* mp = s_mnk + (rg + 4 * t) * Fn + c0;
                #pragma unroll
                for (int q = 0; q < 4; ++q) {
                    float4 z = *(const float4*)(zp + q * 4);
                    float4 m = *(const float4*)(mp + q * 4);
                    d[t] += z.x * wA[4*q] + z.y * wA[4*q+1] + z.z * wA[4*q+2] + z.w * wA[4*q+3];
                    e[t] += m.x * wB[4*q] + m.y * wB[4*q+1] + m.z * wB[4*q+2] + m.w * wB[4*q+3];
                }
            }
        }
        #pragma unroll
        for (int t = 0; t < 8; ++t) {
            float v = d[t] + e[t] * (1.f / 64.f);
            v = v > 0.f ? v : 0.01f * v;
            out2[(size_t)b * Kn * Fn + (rg + 4 * t) * Fn + f] = v;
        }
    }
}

extern "C" void kernel_launch(void* const* d_in, const int* in_sizes, int n_in,
                              void* d_out, int out_size, void* d_ws, size_t ws_size,
                              hipStream_t stream) {
    const float* z_mk     = (const float*)d_in[0];
    const float* z_m      = (const float*)d_in[1];
    const float* z_k      = (const float*)d_in[2];
    const float* Wedge    = (const float*)d_in[3];
    const float* Wm       = (const float*)d_in[4];
    const float* Wk       = (const float*)d_in[5];
    const float* Wself_m  = (const float*)d_in[6];
    const float* Wself_k  = (const float*)d_in[7];
    const float* Wneigh_m = (const float*)d_in[8];
    const float* Wneigh_k = (const float*)d_in[9];

    float* out0 = (float*)d_out;                       // (512, 2048, 64)
    float* out1 = out0 + (size_t)BS * ROWS * Fn;       // (512, 64, 64)
    float* out2 = out1 + (size_t)BS * Mn * Fn;         // (512, 32, 64)
    float* ws   = (float*)d_ws;                        // 25.2 MB used

    gnn_edges<<<BS * 4, 256, 0, stream>>>(z_mk, z_m, z_k, Wedge, Wm, Wk, out0, ws);
    gnn_nodes<<<BS, 256, 0, stream>>>(z_m, z_k, Wself_m, Wself_k,
                                      Wneigh_m, Wneigh_k, ws, out1, out2);
}

// Round 7
// 196.317 us; speedup vs baseline: 1.2366x; 1.2366x over previous
//
#include <hip/hip_runtime.h>

typedef float  f32x4_t  __attribute__((ext_vector_type(4)));
typedef __bf16 bf16x8_t __attribute__((ext_vector_type(8)));

#define BS   512
#define Mn   64
#define Kn   32
#define Fn   64
#define ROWS 2048   // Mn*Kn

__device__ __forceinline__ void load_tile(const float* __restrict__ z_mk,
                                          size_t rb, int low, int gr, float4* r) {
    const float* zr = z_mk + (rb + low) * 64;
    r[0] = *(const float4*)(zr + 0 * 32 + gr * 8);
    r[1] = *(const float4*)(zr + 0 * 32 + gr * 8 + 4);
    r[2] = *(const float4*)(zr + 1 * 32 + gr * 8);
    r[3] = *(const float4*)(zr + 1 * 32 + gr * 8 + 4);
}

// ---------------- Kernel A: edges + messages -----------------
// grid 2048 = 512 batches x 4 m-quarters; 256 threads (4 waves).
// Cross-iteration software pipeline: next tile-pair's 8 global loads issued
// BEFORE the current pair's MFMA+epilogue. launch_bounds min-blocks=3 keeps
// the register budget at ~170 so the prefetch does NOT spill (round-6 lesson:
// (256,4) forced a 64-VGPR cap -> 200MB scratch traffic). Actual VGPR should
// land <=128, letting the HW still resident 4 blocks/CU (LDS 34KB*4 < 160KB).
__global__ __launch_bounds__(256, 3) void gnn_edges(
    const float* __restrict__ z_mk, const float* __restrict__ z_m,
    const float* __restrict__ z_k,  const float* __restrict__ Wedge,
    const float* __restrict__ Wm,   const float* __restrict__ Wk,
    float* __restrict__ out0, float* __restrict__ ws)
{
    __shared__ __align__(16) float s_all[8480];
    float* s_wzm = s_all;          // 1024 (16 x 64)
    float* s_wzk = s_all + 1024;   // 2080 (32 x 65)
    float* U     = s_all + 3104;   // 5376 phase-unioned

    const int tid  = threadIdx.x;
    const int bid  = blockIdx.x;
    const int b    = bid >> 2;
    const int mq   = bid & 3;      // m-quarter
    const int lane = tid & 63;
    const int wave = tid >> 6;     // 0..3
    const int low  = lane & 15;
    const int gr   = lane >> 4;
    const int f    = lane;

    // ---- P0: stage z_m quarter (16 rows) + z_k (32 rows) ----
    {
        const float4* src = (const float4*)(z_m + ((size_t)b * Mn + mq * 16) * Fn);
        float4* dst = (float4*)U;
        for (int i = tid; i < 16 * Fn / 4; i += 256) dst[i] = src[i];
        const float4* src2 = (const float4*)(z_k + (size_t)b * Kn * Fn);
        float4* dst2 = (float4*)(U + 1024);
        for (int i = tid; i < Kn * Fn / 4; i += 256) dst2[i] = src2[i];
    }
    __syncthreads();

    // ---- P1: Wz_m (16 rows), Wz_k (32 rows), fp32 ----
    {
        float acc[4] = {0.f, 0.f, 0.f, 0.f};
        for (int c0 = 0; c0 < Fn; c0 += 16) {
            float w[16];
            #pragma unroll
            for (int cc = 0; cc < 16; ++cc) w[cc] = Wm[(c0 + cc) * Fn + f];
            #pragma unroll
            for (int t = 0; t < 4; ++t) {
                const float* zp = U + (wave + 4 * t) * Fn + c0;
                #pragma unroll
                for (int q = 0; q < 4; ++q) {
                    float4 z = *(const float4*)(zp + q * 4);
                    acc[t] += z.x * w[4*q] + z.y * w[4*q+1] + z.z * w[4*q+2] + z.w * w[4*q+3];
                }
            }
        }
        #pragma unroll
        for (int t = 0; t < 4; ++t) s_wzm[(wave + 4 * t) * Fn + f] = acc[t];
    }
    {
        float acc[8] = {0.f};
        for (int c0 = 0; c0 < Fn; c0 += 16) {
            float w[16];
            #pragma unroll
            for (int cc = 0; cc < 16; ++cc) w[cc] = Wk[(c0 + cc) * Fn + f];
            #pragma unroll
            for (int t = 0; t < 8; ++t) {
                const float* zp = U + 1024 + (wave + 4 * t) * Fn + c0;
                #pragma unroll
                for (int q = 0; q < 4; ++q) {
                    float4 z = *(const float4*)(zp + q * 4);
                    acc[t] += z.x * w[4*q] + z.y * w[4*q+1] + z.z * w[4*q+2] + z.w * w[4*q+3];
                }
            }
        }
        #pragma unroll
        for (int t = 0; t < 8; ++t) s_wzk[(wave + 4 * t) * 65 + f] = acc[t];
    }
    __syncthreads();   // z staging dead

    // ---- P2: stage Wedge (padded 65) ----
    for (int i = tid; i < Fn * Fn; i += 256)
        U[(i >> 6) * 65 + (i & 63)] = Wedge[i];
    __syncthreads();

    // ---- P3: B fragments ----
    bf16x8_t Bf[2][4];
    #pragma unroll
    for (int ks = 0; ks < 2; ++ks)
        #pragma unroll
        for (int n = 0; n < 4; ++n)
            #pragma unroll
            for (int i = 0; i < 8; ++i)
                Bf[ks][n][i] = (__bf16)U[(ks * 32 + gr * 8 + i) * 65 + n * 16 + low];
    __syncthreads();   // Wedge dead

    // ---- P4: zero message accumulators ----
    for (int i = tid; i < 3072; i += 256) U[i] = 0.f;

    // hoist loop-invariant Wz_k values: kk = p*16 + gr*4 + j, fc = n*16 + low
    const int p = wave & 1;
    float wzk_r[4][4];
    #pragma unroll
    for (int j = 0; j < 4; ++j)
        #pragma unroll
        for (int n = 0; n < 4; ++n)
            wzk_r[j][n] = s_wzk[(p * 16 + gr * 4 + j) * 65 + n * 16 + low];
    __syncthreads();

    float* s_mnm = U;                      // 16 x 64
    float* s_mnk = U + 1024;               // 32 x 64
    float* scr   = U + 3072 + wave * 576;  // 16 rows x 36 stride

    // ---- P5: main edge loop, tile pairs, 1-pair-deep pipeline ----
    float nk[4][4];
    #pragma unroll
    for (int j = 0; j < 4; ++j)
        #pragma unroll
        for (int n = 0; n < 4; ++n) nk[j][n] = 0.f;

    const size_t browbase = (size_t)b * ROWS + (size_t)mq * 512;

    auto process = [&](const float4* rr, int ml, size_t rb) {
        bf16x8_t A[2];
        #pragma unroll
        for (int ks = 0; ks < 2; ++ks) {
            float4 qa = rr[2*ks], qb = rr[2*ks+1];
            A[ks][0] = (__bf16)qa.x; A[ks][1] = (__bf16)qa.y;
            A[ks][2] = (__bf16)qa.z; A[ks][3] = (__bf16)qa.w;
            A[ks][4] = (__bf16)qb.x; A[ks][5] = (__bf16)qb.y;
            A[ks][6] = (__bf16)qb.z; A[ks][7] = (__bf16)qb.w;
        }

        f32x4_t acc[4];
        #pragma unroll
        for (int n = 0; n < 4; ++n) acc[n] = (f32x4_t){0.f, 0.f, 0.f, 0.f};
        #pragma unroll
        for (int ks = 0; ks < 2; ++ks)
            #pragma unroll
            for (int n = 0; n < 4; ++n)
                acc[n] = __builtin_amdgcn_mfma_f32_16x16x32_bf16(A[ks], Bf[ks][n], acc[n], 0, 0, 0);

        // epilogue: msgs + LDS transpose -> nontemporal full-line stores
        #pragma unroll
        for (int h = 0; h < 2; ++h) {
            #pragma unroll
            for (int nn = 0; nn < 2; ++nn) {
                const int n  = h * 2 + nn;
                const int fc = n * 16 + low;
                const float wmv = s_wzm[ml * Fn + fc];
                float snm = 0.f;
                #pragma unroll
                for (int j = 0; j < 4; ++j) {
                    float e = acc[n][j] + wmv + wzk_r[j][n];
                    e = e > 0.f ? e : 0.01f * e;
                    scr[(gr * 4 + j) * 36 + nn * 16 + low] = e;
                    nk[j][n] += e;
                    snm += e;
                }
                snm += __shfl_xor(snm, 16);
                snm += __shfl_xor(snm, 32);
                if (gr == 0) atomicAdd(&s_mnm[ml * Fn + fc], snm);
            }
            __builtin_amdgcn_wave_barrier();
            #pragma unroll
            for (int q = 0; q < 2; ++q) {
                f32x4_t v = *(const f32x4_t*)(scr + (q * 8 + (lane >> 3)) * 36 + (lane & 7) * 4);
                __builtin_nontemporal_store(v,
                    (f32x4_t*)(out0 + (rb + q * 8 + (lane >> 3)) * 64 + h * 32 + (lane & 7) * 4));
            }
            __builtin_amdgcn_wave_barrier();
        }
    };

    float4 cur0[4], cur1[4], nxt0[4], nxt1[4];
    load_tile(z_mk, browbase + (size_t)(wave)     * 16, low, gr, cur0);
    load_tile(z_mk, browbase + (size_t)(wave + 4) * 16, low, gr, cur1);

    #pragma unroll 1
    for (int it = 0; it < 4; ++it) {
        const int t0 = wave + 8 * it;
        // issue next pair's 8 loads BEFORE any compute/epilogue of this pair
        if (it + 1 < 4) {
            load_tile(z_mk, browbase + (size_t)(t0 + 8)  * 16, low, gr, nxt0);
            load_tile(z_mk, browbase + (size_t)(t0 + 12) * 16, low, gr, nxt1);
        }

        process(cur0, t0 >> 1,       browbase + (size_t)t0 * 16);
        process(cur1, (t0 + 4) >> 1, browbase + (size_t)(t0 + 4) * 16);

        #pragma unroll
        for (int i = 0; i < 4; ++i) { cur0[i] = nxt0[i]; cur1[i] = nxt1[i]; }
    }

    // flush per-lane msg_nk partials into LDS
    #pragma unroll
    for (int j = 0; j < 4; ++j)
        #pragma unroll
        for (int n = 0; n < 4; ++n)
            atomicAdd(&s_mnk[(p * 16 + gr * 4 + j) * Fn + n * 16 + low], nk[j][n]);
    __syncthreads();

    // ---- P6: messages to workspace ----
    {
        float* dm = ws + (size_t)b * (Mn * Fn) + mq * 16 * Fn;       // complete rows
        for (int i = tid; i < 1024; i += 256) dm[i] = s_mnm[i];
        float* dk = ws + (size_t)BS * Mn * Fn + ((size_t)mq * BS + b) * (Kn * Fn); // partial
        for (int i = tid; i < 2048; i += 256) dk[i] = s_mnk[i];
    }
}

// ---------------- Kernel B: node updates -----------------
__global__ __launch_bounds__(256, 2) void gnn_nodes(
    const float* __restrict__ z_m, const float* __restrict__ z_k,
    const float* __restrict__ Wself_m, const float* __restrict__ Wself_k,
    const float* __restrict__ Wneigh_m, const float* __restrict__ Wneigh_k,
    const float* __restrict__ ws,
    float* __restrict__ out1, float* __restrict__ out2)
{
    __shared__ __align__(16) float s[12288]; // zm 4096 | zk 2048 | mnm 4096 | mnk 2048
    float* s_zm  = s;
    float* s_zk  = s + 4096;
    float* s_mnm = s + 6144;
    float* s_mnk = s + 10240;

    const int tid  = threadIdx.x;
    const int b    = blockIdx.x;
    const int lane = tid & 63;
    const int wave = tid >> 6;
    const int f    = lane;
    const int rg   = wave;

    {
        const float4* src = (const float4*)(z_m + (size_t)b * Mn * Fn);
        for (int i = tid; i < Mn * Fn / 4; i += 256) ((float4*)s_zm)[i] = src[i];
        const float4* src2 = (const float4*)(z_k + (size_t)b * Kn * Fn);
        for (int i = tid; i < Kn * Fn / 4; i += 256) ((float4*)s_zk)[i] = src2[i];
        const float4* srcm = (const float4*)(ws + (size_t)b * Mn * Fn);
        for (int i = tid; i < Mn * Fn / 4; i += 256) ((float4*)s_mnm)[i] = srcm[i];
        const float* base = ws + (size_t)BS * Mn * Fn;
        const float* p0 = base + ((size_t)0 * BS + b) * (Kn * Fn);
        const float* p1 = base + ((size_t)1 * BS + b) * (Kn * Fn);
        const float* p2 = base + ((size_t)2 * BS + b) * (Kn * Fn);
        const float* p3 = base + ((size_t)3 * BS + b) * (Kn * Fn);
        for (int i = tid; i < Kn * Fn; i += 256) s_mnk[i] = p0[i] + p1[i] + p2[i] + p3[i];
    }
    __syncthreads();

    // out1: rows rg + 4t, t=0..15
    {
        float d[16], e[16];
        #pragma unroll
        for (int t = 0; t < 16; ++t) { d[t] = 0.f; e[t] = 0.f; }
        for (int c0 = 0; c0 < Fn; c0 += 16) {
            float wA[16], wB[16];
            #pragma unroll
            for (int cc = 0; cc < 16; ++cc) {
                wA[cc] = Wself_m[(c0 + cc) * Fn + f];
                wB[cc] = Wneigh_m[(c0 + cc) * Fn + f];
            }
            #pragma unroll
            for (int t = 0; t < 16; ++t) {
                const float* zp = s_zm + (rg + 4 * t) * Fn + c0;
                const float* mp = s_mnm + (rg + 4 * t) * Fn + c0;
                #pragma unroll
                for (int q = 0; q < 4; ++q) {
                    float4 z = *(const float4*)(zp + q * 4);
                    float4 m = *(const float4*)(mp + q * 4);
                    d[t] += z.x * wA[4*q] + z.y * wA[4*q+1] + z.z * wA[4*q+2] + z.w * wA[4*q+3];
                    e[t] += m.x * wB[4*q] + m.y * wB[4*q+1] + m.z * wB[4*q+2] + m.w * wB[4*q+3];
                }
            }
        }
        #pragma unroll
        for (int t = 0; t < 16; ++t) {
            float v = d[t] + e[t] * (1.f / 32.f);
            v = v > 0.f ? v : 0.01f * v;
            out1[(size_t)b * Mn * Fn + (rg + 4 * t) * Fn + f] = v;
        }
    }
    // out2: rows rg + 4t, t=0..7
    {
        float d[8], e[8];
        #pragma unroll
        for (int t = 0; t < 8; ++t) { d[t] = 0.f; e[t] = 0.f; }
        for (int c0 = 0; c0 < Fn; c0 += 16) {
            float wA[16], wB[16];
            #pragma unroll
            for (int cc = 0; cc < 16; ++cc) {
                wA[cc] = Wself_k[(c0 + cc) * Fn + f];
                wB[cc] = Wneigh_k[(c0 + cc) * Fn + f];
            }
            #pragma unroll
            for (int t = 0; t < 8; ++t) {
                const float* zp = s_zk + (rg + 4 * t) * Fn + c0;
                const float* mp = s_mnk + (rg + 4 * t) * Fn + c0;
                #pragma unroll
                for (int q = 0; q < 4; ++q) {
                    float4 z = *(const float4*)(zp + q * 4);
                    float4 m = *(const float4*)(mp + q * 4);
                    d[t] += z.x * wA[4*q] + z.y * wA[4*q+1] + z.z * wA[4*q+2] + z.w * wA[4*q+3];
                    e[t] += m.x * wB[4*q] + m.y * wB[4*q+1] + m.z * wB[4*q+2] + m.w * wB[4*q+3];
                }
            }
        }
        #pragma unroll
        for (int t = 0; t < 8; ++t) {
            float v = d[t] + e[t] * (1.f / 64.f);
            v = v > 0.f ? v : 0.01f * v;
            out2[(size_t)b * Kn * Fn + (rg + 4 * t) * Fn + f] = v;
        }
    }
}

extern "C" void kernel_launch(void* const* d_in, const int* in_sizes, int n_in,
                              void* d_out, int out_size, void* d_ws, size_t ws_size,
                              hipStream_t stream) {
    const float* z_mk     = (const float*)d_in[0];
    const float* z_m      = (const float*)d_in[1];
    const float* z_k      = (const float*)d_in[2];
    const float* Wedge    = (const float*)d_in[3];
    const float* Wm       = (const float*)d_in[4];
    const float* Wk       = (const float*)d_in[5];
    const float* Wself_m  = (const float*)d_in[6];
    const float* Wself_k  = (const float*)d_in[7];
    const float* Wneigh_m = (const float*)d_in[8];
    const float* Wneigh_k = (const float*)d_in[9];

    float* out0 = (float*)d_out;                       // (512, 2048, 64)
    float* out1 = out0 + (size_t)BS * ROWS * Fn;       // (512, 64, 64)
    float* out2 = out1 + (size_t)BS * Mn * Fn;         // (512, 32, 64)
    float* ws   = (float*)d_ws;                        // 25.2 MB used

    gnn_edges<<<BS * 4, 256, 0, stream>>>(z_mk, z_m, z_k, Wedge, Wm, Wk, out0, ws);
    gnn_nodes<<<BS, 256, 0, stream>>>(z_m, z_k, Wself_m, Wself_k,
                                      Wneigh_m, Wneigh_k, ws, out1, out2);
}

// Round 9
// 191.626 us; speedup vs baseline: 1.2668x; 1.0245x over previous
//
#include <hip/hip_runtime.h>

typedef float  f32x4_t  __attribute__((ext_vector_type(4)));
typedef __bf16 bf16x8_t __attribute__((ext_vector_type(8)));

#define BS   512
#define Mn   64
#define Kn   32
#define Fn   64
#define ROWS 2048   // Mn*Kn

// ws layout (floats)
#define WS_WZM  ((size_t)0)                       // 512*64*64  Wz_m
#define WS_WZK  ((size_t)512*4096)                // 512*32*64  Wz_k
#define WS_MNM  (WS_WZK + (size_t)512*2048)       // 512*64*64  msg_nm
#define WS_MNK4 (WS_MNM + (size_t)512*4096)       // 4*512*32*64 msg_nk partials
// total = 9,437,184 floats = 37.7 MB

typedef const __attribute__((address_space(1))) void gas_void;
typedef __attribute__((address_space(3))) void las_void;

// ---------------- Kernel P: per-batch head matmuls -> ws ----------------
__global__ __launch_bounds__(256, 2) void gnn_pre(
    const float* __restrict__ z_m, const float* __restrict__ z_k,
    const float* __restrict__ Wm,  const float* __restrict__ Wk,
    float* __restrict__ ws)
{
    __shared__ __align__(16) float s[6144];
    float* s_zm = s;            // 4096
    float* s_zk = s + 4096;     // 2048
    const int tid = threadIdx.x, b = blockIdx.x;
    const int lane = tid & 63, wave = tid >> 6;
    const int f = lane, rg = wave;

    {
        const float4* a = (const float4*)(z_m + (size_t)b * 4096);
        for (int i = tid; i < 1024; i += 256) ((float4*)s_zm)[i] = a[i];
        const float4* c = (const float4*)(z_k + (size_t)b * 2048);
        for (int i = tid; i < 512; i += 256) ((float4*)s_zk)[i] = c[i];
    }
    __syncthreads();

    float am[16], ak[8];
    #pragma unroll
    for (int t = 0; t < 16; ++t) am[t] = 0.f;
    #pragma unroll
    for (int t = 0; t < 8; ++t) ak[t] = 0.f;

    for (int c0 = 0; c0 < 64; c0 += 16) {
        float wm[16], wk[16];
        #pragma unroll
        for (int cc = 0; cc < 16; ++cc) {
            wm[cc] = Wm[(c0 + cc) * 64 + f];
            wk[cc] = Wk[(c0 + cc) * 64 + f];
        }
        #pragma unroll
        for (int t = 0; t < 16; ++t) {
            const float* zp = s_zm + (rg + 4 * t) * 64 + c0;
            #pragma unroll
            for (int q = 0; q < 4; ++q) {
                float4 z = *(const float4*)(zp + q * 4);
                am[t] += z.x * wm[4*q] + z.y * wm[4*q+1] + z.z * wm[4*q+2] + z.w * wm[4*q+3];
            }
        }
        #pragma unroll
        for (int t = 0; t < 8; ++t) {
            const float* zp = s_zk + (rg + 4 * t) * 64 + c0;
            #pragma unroll
            for (int q = 0; q < 4; ++q) {
                float4 z = *(const float4*)(zp + q * 4);
                ak[t] += z.x * wk[4*q] + z.y * wk[4*q+1] + z.z * wk[4*q+2] + z.w * wk[4*q+3];
            }
        }
    }
    #pragma unroll
    for (int t = 0; t < 16; ++t)
        ws[WS_WZM + (size_t)b * 4096 + (rg + 4 * t) * 64 + f] = am[t];
    #pragma unroll
    for (int t = 0; t < 8; ++t)
        ws[WS_WZK + (size_t)b * 2048 + (rg + 4 * t) * 64 + f] = ak[t];
}

// ---------------- Kernel A: edges + messages -----------------
// grid 2048 = 512 batches x 4 m-quarters; 256 threads (4 waves).
// Wave-local slab pipeline over 8 slabs of 64 rows; NO barriers in main loop.
// Stage via global_load_lds (async, 16B) with pre-swizzled global source so
// the XOR'd LDS layout gives conflict-free ds_read_b128 A-fragments
// (chunk_phys = chunk_logical ^ (row&15); both-sides-or-neither rule).
// Counted vmcnt: steady queue = [stage(s):4][stores(s-1):4][stage(s+1):4]
// -> vmcnt(8) drains exactly stage(s); stores never drained mid-loop.
// Epilogue writes transposed outputs into the (now dead) slab buffer, then
// 4x contiguous-1KB NT stores per wave. DS ops within a wave execute in
// order -> RAW through LDS without waits; lgkmcnt(0) before each stage
// protects the previous storepass reads from async LDS-write overlap.
__global__ __launch_bounds__(256, 3) void gnn_edges(
    const float* __restrict__ z_mk, const float* __restrict__ Wedge,
    float* __restrict__ out0, float* __restrict__ ws)
{
    __shared__ __align__(16) float s_all[12288];
    float* bufA  = s_all;            // 4096 (slab even)
    float* bufB  = s_all + 4096;     // 4096 (slab odd)
    float* s_wzm = s_all + 8192;     // 1024 (16 x 64)
    float* s_mnm = s_all + 9216;     // 1024
    float* s_mnk = s_all + 10240;    // 2048

    const int tid  = threadIdx.x;
    const int bid  = blockIdx.x;
    const int b    = bid >> 2;
    const int mq   = bid & 3;
    const int lane = tid & 63;
    const int w    = tid >> 6;      // 0..3
    const int llo  = lane & 15;
    const int lhi  = lane >> 4;
    const int low  = llo, gr = lhi;
    const int p    = w & 1;

    // ---- head: zeros, Wz_m to LDS, Wz_k to regs, B frags from global ----
    for (int i = tid; i < 3072; i += 256) s_mnm[i] = 0.f;   // mnm+mnk contiguous
    {
        const float4* src = (const float4*)(ws + WS_WZM + ((size_t)b * Mn + mq * 16) * Fn);
        ((float4*)s_wzm)[tid] = src[tid];
    }
    float wzk_r[4][4];
    {
        const float* wk = ws + WS_WZK + (size_t)b * Kn * Fn;
        #pragma unroll
        for (int j = 0; j < 4; ++j)
            #pragma unroll
            for (int n = 0; n < 4; ++n)
                wzk_r[j][n] = wk[(p * 16 + gr * 4 + j) * 64 + n * 16 + low];
    }
    bf16x8_t Bf[2][4];
    #pragma unroll
    for (int ks = 0; ks < 2; ++ks)
        #pragma unroll
        for (int n = 0; n < 4; ++n)
            #pragma unroll
            for (int i = 0; i < 8; ++i)
                Bf[ks][n][i] = (__bf16)Wedge[(ks * 32 + gr * 8 + i) * 64 + n * 16 + low];
    __syncthreads();

    const size_t blockrow0 = (size_t)b * ROWS + (size_t)mq * 512;
    const float* zsrc = z_mk + blockrow0 * 64;

    float nk[4][4];
    #pragma unroll
    for (int j = 0; j < 4; ++j)
        #pragma unroll
        for (int n = 0; n < 4; ++n) nk[j][n] = 0.f;

    // stage one 64-row slab: this wave fetches its own 16 rows (4 x 1KB)
    auto stage = [&](float* buf, int s) {
        #pragma unroll
        for (int i = 0; i < 4; ++i) {
            const int R   = w * 16 + i * 4 + lhi;       // slab-local row
            const int swz = llo ^ (i * 4 + lhi);        // chunk_phys source
            const float* gp = zsrc + ((size_t)s * 64 + R) * 64 + swz * 4;
            float* lp = buf + (w * 4 + i) * 256;        // wave-uniform dst
            __builtin_amdgcn_global_load_lds((gas_void*)gp, (las_void*)lp, 16, 0, 0);
        }
    };

    stage(bufA, 0);

    #pragma unroll 1
    for (int s = 0; s < 8; ++s) {
        float* bc = (s & 1) ? bufB : bufA;

        if (s < 7) {
            asm volatile("s_waitcnt lgkmcnt(0)" ::: "memory");
            __builtin_amdgcn_sched_barrier(0);
            stage((s & 1) ? bufA : bufB, s + 1);
        }
        if (s == 0 || s == 7) asm volatile("s_waitcnt vmcnt(4)" ::: "memory");
        else                  asm volatile("s_waitcnt vmcnt(8)" ::: "memory");
        __builtin_amdgcn_sched_barrier(0);

        // A fragments from swizzled LDS (conflict-free b128 reads)
        bf16x8_t A[2];
        const int arow = (w * 16 + low) * 64;
        #pragma unroll
        for (int ks = 0; ks < 2; ++ks) {
            f32x4_t qa = *(const f32x4_t*)(bc + arow + (((ks * 8 + gr * 2 + 0) ^ low) << 2));
            f32x4_t qb = *(const f32x4_t*)(bc + arow + (((ks * 8 + gr * 2 + 1) ^ low) << 2));
            A[ks][0] = (__bf16)qa[0]; A[ks][1] = (__bf16)qa[1];
            A[ks][2] = (__bf16)qa[2]; A[ks][3] = (__bf16)qa[3];
            A[ks][4] = (__bf16)qb[0]; A[ks][5] = (__bf16)qb[1];
            A[ks][6] = (__bf16)qb[2]; A[ks][7] = (__bf16)qb[3];
        }

        f32x4_t acc[4];
        #pragma unroll
        for (int n = 0; n < 4; ++n) acc[n] = (f32x4_t){0.f, 0.f, 0.f, 0.f};
        #pragma unroll
        for (int ks = 0; ks < 2; ++ks)
            #pragma unroll
            for (int n = 0; n < 4; ++n)
                acc[n] = __builtin_amdgcn_mfma_f32_16x16x32_bf16(A[ks], Bf[ks][n], acc[n], 0, 0, 0);

        const int ml = (s * 4 + w) >> 1;   // block-local m of this tile

        // epilogue: e -> LDS (transposed, own-tile region now dead) + messages
        #pragma unroll
        for (int n = 0; n < 4; ++n) {
            const int fc = n * 16 + low;
            const float wmv = s_wzm[ml * 64 + fc];
            float snm = 0.f;
            #pragma unroll
            for (int j = 0; j < 4; ++j) {
                float e = acc[n][j] + wmv + wzk_r[j][n];
                e = e > 0.f ? e : 0.01f * e;
                bc[(w * 16 + gr * 4 + j) * 64 + fc] = e;
                nk[j][n] += e;
                snm += e;
            }
            snm += __shfl_xor(snm, 16);
            snm += __shfl_xor(snm, 32);
            if (gr == 0) atomicAdd(&s_mnm[ml * 64 + fc], snm);
        }

        // storepass: own 16 rows, 4 x contiguous-1KB NT bursts per wave
        #pragma unroll
        for (int r = 0; r < 4; ++r) {
            const int lrow = w * 16 + lhi + 4 * r;
            f32x4_t v = *(const f32x4_t*)(bc + lrow * 64 + llo * 4);
            __builtin_nontemporal_store(v,
                (f32x4_t*)(out0 + (blockrow0 + (size_t)s * 64 + lrow) * 64 + llo * 4));
        }
    }

    // flush per-lane msg_nk partials into LDS
    #pragma unroll
    for (int j = 0; j < 4; ++j)
        #pragma unroll
        for (int n = 0; n < 4; ++n)
            atomicAdd(&s_mnk[(p * 16 + gr * 4 + j) * 64 + n * 16 + low], nk[j][n]);
    __syncthreads();

    // messages to workspace
    {
        float* dm = ws + WS_MNM + (size_t)b * 4096 + mq * 1024;      // complete rows
        for (int i = tid; i < 1024; i += 256) dm[i] = s_mnm[i];
        float* dk = ws + WS_MNK4 + ((size_t)mq * BS + b) * 2048;     // partial
        for (int i = tid; i < 2048; i += 256) dk[i] = s_mnk[i];
    }
}

// ---------------- Kernel B: node updates -----------------
__global__ __launch_bounds__(256, 2) void gnn_nodes(
    const float* __restrict__ z_m, const float* __restrict__ z_k,
    const float* __restrict__ Wself_m, const float* __restrict__ Wself_k,
    const float* __restrict__ Wneigh_m, const float* __restrict__ Wneigh_k,
    const float* __restrict__ ws,
    float* __restrict__ out1, float* __restrict__ out2)
{
    __shared__ __align__(16) float s[12288]; // zm 4096 | zk 2048 | mnm 4096 | mnk 2048
    float* s_zm  = s;
    float* s_zk  = s + 4096;
    float* s_mnm = s + 6144;
    float* s_mnk = s + 10240;

    const int tid  = threadIdx.x;
    const int b    = blockIdx.x;
    const int lane = tid & 63;
    const int wave = tid >> 6;
    const int f    = lane;
    const int rg   = wave;

    {
        const float4* src = (const float4*)(z_m + (size_t)b * Mn * Fn);
        for (int i = tid; i < Mn * Fn / 4; i += 256) ((float4*)s_zm)[i] = src[i];
        const float4* src2 = (const float4*)(z_k + (size_t)b * Kn * Fn);
        for (int i = tid; i < Kn * Fn / 4; i += 256) ((float4*)s_zk)[i] = src2[i];
        const float4* srcm = (const float4*)(ws + WS_MNM + (size_t)b * Mn * Fn);
        for (int i = tid; i < Mn * Fn / 4; i += 256) ((float4*)s_mnm)[i] = srcm[i];
        const float* base = ws + WS_MNK4;
        const float* p0 = base + ((size_t)0 * BS + b) * (Kn * Fn);
        const float* p1 = base + ((size_t)1 * BS + b) * (Kn * Fn);
        const float* p2 = base + ((size_t)2 * BS + b) * (Kn * Fn);
        const float* p3 = base + ((size_t)3 * BS + b) * (Kn * Fn);
        for (int i = tid; i < Kn * Fn; i += 256) s_mnk[i] = p0[i] + p1[i] + p2[i] + p3[i];
    }
    __syncthreads();

    // out1: rows rg + 4t, t=0..15
    {
        float d[16], e[16];
        #pragma unroll
        for (int t = 0; t < 16; ++t) { d[t] = 0.f; e[t] = 0.f; }
        for (int c0 = 0; c0 < Fn; c0 += 16) {
            float wA[16], wB[16];
            #pragma unroll
            for (int cc = 0; cc < 16; ++cc) {
                wA[cc] = Wself_m[(c0 + cc) * Fn + f];
                wB[cc] = Wneigh_m[(c0 + cc) * Fn + f];
            }
            #pragma unroll
            for (int t = 0; t < 16; ++t) {
                const float* zp = s_zm + (rg + 4 * t) * Fn + c0;
                const float* mp = s_mnm + (rg + 4 * t) * Fn + c0;
                #pragma unroll
                for (int q = 0; q < 4; ++q) {
                    float4 z = *(const float4*)(zp + q * 4);
                    float4 m = *(const float4*)(mp + q * 4);
                    d[t] += z.x * wA[4*q] + z.y * wA[4*q+1] + z.z * wA[4*q+2] + z.w * wA[4*q+3];
                    e[t] += m.x * wB[4*q] + m.y * wB[4*q+1] + m.z * wB[4*q+2] + m.w * wB[4*q+3];
                }
            }
        }
        #pragma unroll
        for (int t = 0; t < 16; ++t) {
            float v = d[t] + e[t] * (1.f / 32.f);
            v = v > 0.f ? v : 0.01f * v;
            out1[(size_t)b * Mn * Fn + (rg + 4 * t) * Fn + f] = v;
        }
    }
    // out2: rows rg + 4t, t=0..7
    {
        float d[8], e[8];
        #pragma unroll
        for (int t = 0; t < 8; ++t) { d[t] = 0.f; e[t] = 0.f; }
        for (int c0 = 0; c0 < Fn; c0 += 16) {
            float wA[16], wB[16];
            #pragma unroll
            for (int cc = 0; cc < 16; ++cc) {
                wA[cc] = Wself_k[(c0 + cc) * Fn + f];
                wB[cc] = Wneigh_k[(c0 + cc) * Fn + f];
            }
            #pragma unroll
            for (int t = 0; t < 8; ++t) {
                const float* zp = s_zk + (rg + 4 * t) * Fn + c0;
                const float* mp = s_mnk + (rg + 4 * t) * Fn + c0;
                #pragma unroll
                for (int q = 0; q < 4; ++q) {
                    float4 z = *(const float4*)(zp + q * 4);
                    float4 m = *(const float4*)(mp + q * 4);
                    d[t] += z.x * wA[4*q] + z.y * wA[4*q+1] + z.z * wA[4*q+2] + z.w * wA[4*q+3];
                    e[t] += m.x * wB[4*q] + m.y * wB[4*q+1] + m.z * wB[4*q+2] + m.w * wB[4*q+3];
                }
            }
        }
        #pragma unroll
        for (int t = 0; t < 8; ++t) {
            float v = d[t] + e[t] * (1.f / 64.f);
            v = v > 0.f ? v : 0.01f * v;
            out2[(size_t)b * Kn * Fn + (rg + 4 * t) * Fn + f] = v;
        }
    }
}

extern "C" void kernel_launch(void* const* d_in, const int* in_sizes, int n_in,
                              void* d_out, int out_size, void* d_ws, size_t ws_size,
                              hipStream_t stream) {
    const float* z_mk     = (const float*)d_in[0];
    const float* z_m      = (const float*)d_in[1];
    const float* z_k      = (const float*)d_in[2];
    const float* Wedge    = (const float*)d_in[3];
    const float* Wm       = (const float*)d_in[4];
    const float* Wk       = (const float*)d_in[5];
    const float* Wself_m  = (const float*)d_in[6];
    const float* Wself_k  = (const float*)d_in[7];
    const float* Wneigh_m = (const float*)d_in[8];
    const float* Wneigh_k = (const float*)d_in[9];

    float* out0 = (float*)d_out;                       // (512, 2048, 64)
    float* out1 = out0 + (size_t)BS * ROWS * Fn;       // (512, 64, 64)
    float* out2 = out1 + (size_t)BS * Mn * Fn;         // (512, 32, 64)
    float* ws   = (float*)d_ws;                        // 37.7 MB used

    gnn_pre<<<BS, 256, 0, stream>>>(z_m, z_k, Wm, Wk, ws);
    gnn_edges<<<BS * 4, 256, 0, stream>>>(z_mk, Wedge, out0, ws);
    gnn_nodes<<<BS, 256, 0, stream>>>(z_m, z_k, Wself_m, Wself_k,
                                      Wneigh_m, Wneigh_k, ws, out1, out2);
}